// Round 4
// baseline (168.452 us; speedup 1.0000x reference)
//
#include <hip/hip_runtime.h>
#include <cstddef>

#define BATCH 512
#define UNITS 512
#define HID   64
#define CHUNKS 2            // batch split across blocks: 2 chunks of 256 rows
#define ROWS_PER_CHUNK (BATCH / CHUNKS)

typedef __bf16 bf16x8 __attribute__((ext_vector_type(8)));
typedef float  f32x4  __attribute__((ext_vector_type(4)));

__device__ __forceinline__ float fast_sigmoid(float v) {
    return 1.0f / (1.0f + __expf(-v));
}
__device__ __forceinline__ float fast_tanh(float v) {
    return 2.0f / (1.0f + __expf(-2.0f * v)) - 1.0f;
}

// Weights live in LDS in MFMA-fragment order (48KB = 6 g x 2 ks x 64 o x 4 lg
// chunks of 16B). chunk slot(g,ks,o,lg) = (g*2+ks)*256 + o*4 + ((lg+o)&3).
//  - staging: global reads 256B-coalesced, ds_write_b128, <=4-way bank alias
//  - per-iter reads: each (g,ks,n) read is a contiguous 1KB wave sweep, 0-conflict
// Registers: accs 64 + A-frags 32 + transient B 24 -> ~140 live, 3 waves/SIMD.
// LDS 48KB -> 3 blocks/CU -> 12 waves/CU (vs R1's 8, which was register-capped:
// 96-VGPR resident weights + 64 acc pushed total ~190 -> 2 waves/SIMD).
__global__ __launch_bounds__(256, 3)
void gru_kernel(const float* __restrict__ x,    const float* __restrict__ h,
                const float* __restrict__ W_ir, const float* __restrict__ b_ir,
                const float* __restrict__ W_hr, const float* __restrict__ b_hr,
                const float* __restrict__ W_iz, const float* __restrict__ b_iz,
                const float* __restrict__ W_hz, const float* __restrict__ b_hz,
                const float* __restrict__ W_in, const float* __restrict__ b_in,
                const float* __restrict__ W_hn, const float* __restrict__ b_hn,
                float* __restrict__ out)
{
    __shared__ __align__(16) unsigned char wlds[6 * 2 * 64 * 4 * 16]; // 48 KB

    const int u     = blockIdx.x >> 1;      // unit
    const int chunk = blockIdx.x & 1;       // batch chunk
    const int tid  = threadIdx.x;
    const int lane = tid & 63;
    const int w    = tid >> 6;
    const int wm   = w >> 1;     // 0..1 : M half
    const int wn   = w & 1;      // 0..1 : N half
    const int lr   = lane & 15;  // row (A) / col (B,D) within fragment
    const int lg   = lane >> 4;  // k-group 0..3

    const float* Wg[6] = {
        W_ir + (size_t)u * 64 * 64, W_hr + (size_t)u * 64 * 64,
        W_iz + (size_t)u * 64 * 64, W_hz + (size_t)u * 64 * 64,
        W_in + (size_t)u * 64 * 64, W_hn + (size_t)u * 64 * 64 };

    // ---- stage weights into LDS fragment layout (coalesced) ----
    // pass p = g*2+ks; thread t -> o = t&63 (lane), lg_s = t>>6 (wave).
    {
      const int o_s  = tid & 63;
      const int lg_s = tid >> 6;
      #pragma unroll
      for (int p = 0; p < 12; ++p) {
        const int g  = p >> 1;
        const int ks = p & 1;
        const int i0 = ks * 32 + lg_s * 8;
        const float* q = Wg[g] + (size_t)i0 * 64 + o_s;   // g is compile-time
        bf16x8 f;
        #pragma unroll
        for (int e = 0; e < 8; ++e) f[e] = (__bf16)q[(size_t)e * 64];
        const int slot = p * 256 + o_s * 4 + ((lg_s + o_s) & 3);
        *(bf16x8*)(wlds + (size_t)slot * 16) = f;
      }
    }

    // ---- per-lane biases (col o fixed per n-fragment) ----
    float brs[2], bzs[2], bins[2], bhns[2];
    int boff[2];   // LDS byte offset (lane part) for B-frag reads, per n
    #pragma unroll
    for (int n = 0; n < 2; ++n) {
      const int o = wn * 32 + n * 16 + lr;
      brs[n]  = b_ir[u * 64 + o] + b_hr[u * 64 + o];
      bzs[n]  = b_iz[u * 64 + o] + b_hz[u * 64 + o];
      bins[n] = b_in[u * 64 + o];
      bhns[n] = b_hn[u * 64 + o];
      boff[n] = (o * 4 + ((lg + o) & 3)) * 16;
    }

    __syncthreads();

    const f32x4 zero4 = { 0.0f, 0.0f, 0.0f, 0.0f };

    for (int it = 0; it < ROWS_PER_CHUNK / 64; ++it) {
      const int brow0 = chunk * ROWS_PER_CHUNK + it * 64 + wm * 32;

      // ---- A fragments: x,h rows -> bf16x8 (8 contiguous k per lane) ----
      bf16x8 ax[2][2], ah[2][2];
      #pragma unroll
      for (int m = 0; m < 2; ++m) {
        const int row = brow0 + m * 16 + lr;
        const float* px = x + ((size_t)row * UNITS + u) * HID;
        const float* ph = h + ((size_t)row * UNITS + u) * HID;
        #pragma unroll
        for (int ks = 0; ks < 2; ++ks) {
          const int i0 = ks * 32 + lg * 8;
          f32x4 xv0 = *(const f32x4*)(px + i0);
          f32x4 xv1 = *(const f32x4*)(px + i0 + 4);
          f32x4 hv0 = *(const f32x4*)(ph + i0);
          f32x4 hv1 = *(const f32x4*)(ph + i0 + 4);
          bf16x8 fx, fh;
          #pragma unroll
          for (int e = 0; e < 4; ++e) {
            fx[e]     = (__bf16)xv0[e];
            fx[4 + e] = (__bf16)xv1[e];
            fh[e]     = (__bf16)hv0[e];
            fh[4 + e] = (__bf16)hv1[e];
          }
          ax[m][ks] = fx;
          ah[m][ks] = fh;
        }
      }

      // ---- MFMA accumulation: B-frags read just-in-time from LDS ----
      f32x4 accr[2][2], accz[2][2], acca[2][2], accb[2][2];
      #pragma unroll
      for (int m = 0; m < 2; ++m)
        #pragma unroll
        for (int n = 0; n < 2; ++n) {
          accr[m][n] = zero4; accz[m][n] = zero4;
          acca[m][n] = zero4; accb[m][n] = zero4;
        }

      #pragma unroll
      for (int ks = 0; ks < 2; ++ks)
        #pragma unroll
        for (int n = 0; n < 2; ++n) {
          const unsigned char* base = wlds + boff[n];
          bf16x8 b0 = *(const bf16x8*)(base + (0 * 2 + ks) * 4096);
          bf16x8 b1 = *(const bf16x8*)(base + (1 * 2 + ks) * 4096);
          bf16x8 b2 = *(const bf16x8*)(base + (2 * 2 + ks) * 4096);
          bf16x8 b3 = *(const bf16x8*)(base + (3 * 2 + ks) * 4096);
          bf16x8 b4 = *(const bf16x8*)(base + (4 * 2 + ks) * 4096);
          bf16x8 b5 = *(const bf16x8*)(base + (5 * 2 + ks) * 4096);
          #pragma unroll
          for (int m = 0; m < 2; ++m) {
            accr[m][n] = __builtin_amdgcn_mfma_f32_16x16x32_bf16(ax[m][ks], b0, accr[m][n], 0, 0, 0);
            accr[m][n] = __builtin_amdgcn_mfma_f32_16x16x32_bf16(ah[m][ks], b1, accr[m][n], 0, 0, 0);
            accz[m][n] = __builtin_amdgcn_mfma_f32_16x16x32_bf16(ax[m][ks], b2, accz[m][n], 0, 0, 0);
            accz[m][n] = __builtin_amdgcn_mfma_f32_16x16x32_bf16(ah[m][ks], b3, accz[m][n], 0, 0, 0);
            acca[m][n] = __builtin_amdgcn_mfma_f32_16x16x32_bf16(ax[m][ks], b4, acca[m][n], 0, 0, 0);
            accb[m][n] = __builtin_amdgcn_mfma_f32_16x16x32_bf16(ah[m][ks], b5, accb[m][n], 0, 0, 0);
          }
        }

      // ---- epilogue: gates + blend, direct store ----
      // D layout (HW-verified m89): col = lane&15, row = (lane>>4)*4 + j
      #pragma unroll
      for (int m = 0; m < 2; ++m)
        #pragma unroll
        for (int n = 0; n < 2; ++n) {
          const int o = wn * 32 + n * 16 + lr;
          #pragma unroll
          for (int j = 0; j < 4; ++j) {
            const int row = brow0 + m * 16 + lg * 4 + j;
            const size_t idx = ((size_t)row * UNITS + u) * HID + o;
            const float rv = fast_sigmoid(accr[m][n][j] + brs[n]);
            const float zv = fast_sigmoid(accz[m][n][j] + bzs[n]);
            const float nv = fast_tanh(acca[m][n][j] + bins[n] +
                                       rv * (accb[m][n][j] + bhns[n]));
            const float hv = h[idx];
            out[idx] = (1.0f - zv) * nv + zv * hv;
          }
        }
    }
}

extern "C" void kernel_launch(void* const* d_in, const int* in_sizes, int n_in,
                              void* d_out, int out_size, void* d_ws, size_t ws_size,
                              hipStream_t stream) {
    const float* x    = (const float*)d_in[0];
    const float* h    = (const float*)d_in[1];
    const float* W_ir = (const float*)d_in[2];
    const float* b_ir = (const float*)d_in[3];
    const float* W_hr = (const float*)d_in[4];
    const float* b_hr = (const float*)d_in[5];
    const float* W_iz = (const float*)d_in[6];
    const float* b_iz = (const float*)d_in[7];
    const float* W_hz = (const float*)d_in[8];
    const float* b_hz = (const float*)d_in[9];
    const float* W_in = (const float*)d_in[10];
    const float* b_in = (const float*)d_in[11];
    const float* W_hn = (const float*)d_in[12];
    const float* b_hn = (const float*)d_in[13];
    float* out = (float*)d_out;

    gru_kernel<<<dim3(UNITS * CHUNKS), dim3(256), 0, stream>>>(
        x, h, W_ir, b_ir, W_hr, b_hr, W_iz, b_iz, W_hz, b_hz,
        W_in, b_in, W_hn, b_hn, out);
}

// Round 5
// 73.306 us; speedup vs baseline: 2.2979x; 2.2979x over previous
//
#include <hip/hip_runtime.h>
#include <cstddef>

#define BATCH 512
#define UNITS 512
#define HID   64

typedef __bf16 bf16x8 __attribute__((ext_vector_type(8)));
typedef float  f32x4  __attribute__((ext_vector_type(4)));

__device__ __forceinline__ float fast_sigmoid(float v) {
    return 1.0f / (1.0f + __expf(-v));
}
__device__ __forceinline__ float fast_tanh(float v) {
    return 2.0f / (1.0f + __expf(-2.0f * v)) - 1.0f;
}

// Grid = 512 blocks (1 unit each) x 512 threads (8 waves = 4M x 2N).
// Wave tile 32 rows x 32 cols; block covers 128 rows/iter, 4 iters.
// Weights in LDS (48KB) in MFMA-fragment order; n-OUTER loop keeps only
// 32 acc regs live -> total ~115 regs/wave -> 4 waves/SIMD -> 2 blocks/CU
// = 16 waves/CU (50%). Compiler budget rule (measured R1-R4):
// VGPR cap = 256/min_waves_per_EU, so launch_bounds(512,2) -> cap 128.
// LDS chunk slot(g,ks,o,lg) = (g*2+ks)*256 + o*4 + ((lg+(o>>2))&3):
//  - reads: each (g,ks,wave) reads a contiguous 1KB sweep, conflict-free
//  - staging writes: 4-way alias max (was 16-way with (lg+o)&3 in R4)
__global__ __launch_bounds__(512, 2)
void gru_kernel(const float* __restrict__ x,    const float* __restrict__ h,
                const float* __restrict__ W_ir, const float* __restrict__ b_ir,
                const float* __restrict__ W_hr, const float* __restrict__ b_hr,
                const float* __restrict__ W_iz, const float* __restrict__ b_iz,
                const float* __restrict__ W_hz, const float* __restrict__ b_hz,
                const float* __restrict__ W_in, const float* __restrict__ b_in,
                const float* __restrict__ W_hn, const float* __restrict__ b_hn,
                float* __restrict__ out)
{
    __shared__ __align__(16) unsigned char wlds[6 * 2 * 64 * 4 * 16]; // 48 KB

    const int u    = blockIdx.x;
    const int tid  = threadIdx.x;
    const int lane = tid & 63;
    const int w    = tid >> 6;   // 0..7
    const int wm   = w >> 1;     // 0..3 : M quarter (32 rows)
    const int wn   = w & 1;      // 0..1 : N half (32 cols)
    const int lr   = lane & 15;  // row (A) / col (B,D) within fragment
    const int lg   = lane >> 4;  // k-group 0..3

    const float* Wg[6] = {
        W_ir + (size_t)u * 64 * 64, W_hr + (size_t)u * 64 * 64,
        W_iz + (size_t)u * 64 * 64, W_hz + (size_t)u * 64 * 64,
        W_in + (size_t)u * 64 * 64, W_hn + (size_t)u * 64 * 64 };

    // ---- stage weights into LDS fragment layout (coalesced 256B reads) ----
    // thread t: o_s = t&63, ig = t>>6 covers i rows ig*8..ig*8+7 in ONE pass
    // per matrix (ks_s = ig>>2, lg_s = ig&3).
    {
      const int o_s  = tid & 63;
      const int ig   = tid >> 6;
      const int ks_s = ig >> 2;
      const int lg_s = ig & 3;
      const int rot  = (lg_s + (o_s >> 2)) & 3;
      #pragma unroll
      for (int g = 0; g < 6; ++g) {
        const float* q = Wg[g] + (size_t)(ig * 8) * 64 + o_s;
        bf16x8 f;
        #pragma unroll
        for (int e = 0; e < 8; ++e) f[e] = (__bf16)q[(size_t)e * 64];
        const int slot = (g * 2 + ks_s) * 256 + o_s * 4 + rot;
        *(bf16x8*)(wlds + (size_t)slot * 16) = f;
      }
    }

    // ---- per-lane biases + LDS read offsets (col o fixed per n) ----
    float brs[2], bzs[2], bins[2], bhns[2];
    int boff[2];
    #pragma unroll
    for (int n = 0; n < 2; ++n) {
      const int o = wn * 32 + n * 16 + lr;
      brs[n]  = b_ir[u * 64 + o] + b_hr[u * 64 + o];
      bzs[n]  = b_iz[u * 64 + o] + b_hz[u * 64 + o];
      bins[n] = b_in[u * 64 + o];
      bhns[n] = b_hn[u * 64 + o];
      boff[n] = (o * 4 + ((lg + (o >> 2)) & 3)) * 16;
    }

    __syncthreads();

    const f32x4 zero4 = { 0.0f, 0.0f, 0.0f, 0.0f };

    #pragma unroll 1
    for (int it = 0; it < 4; ++it) {
      const int brow0 = it * 128 + wm * 32;

      // ---- A fragments: x,h rows -> bf16x8 (8 contiguous k per lane) ----
      bf16x8 ax[2][2], ah[2][2];
      #pragma unroll
      for (int m = 0; m < 2; ++m) {
        const int row = brow0 + m * 16 + lr;
        const float* px = x + ((size_t)row * UNITS + u) * HID;
        const float* ph = h + ((size_t)row * UNITS + u) * HID;
        #pragma unroll
        for (int ks = 0; ks < 2; ++ks) {
          const int i0 = ks * 32 + lg * 8;
          f32x4 xv0 = *(const f32x4*)(px + i0);
          f32x4 xv1 = *(const f32x4*)(px + i0 + 4);
          f32x4 hv0 = *(const f32x4*)(ph + i0);
          f32x4 hv1 = *(const f32x4*)(ph + i0 + 4);
          bf16x8 fx, fh;
          #pragma unroll
          for (int e = 0; e < 4; ++e) {
            fx[e]     = (__bf16)xv0[e];
            fx[4 + e] = (__bf16)xv1[e];
            fh[e]     = (__bf16)hv0[e];
            fh[4 + e] = (__bf16)hv1[e];
          }
          ax[m][ks] = fx;
          ah[m][ks] = fh;
        }
      }

      // ---- n-outer: 32 acc regs live at a time, epilogue per n ----
      #pragma unroll
      for (int n = 0; n < 2; ++n) {
        f32x4 accr[2], accz[2], acca[2], accb[2];
        #pragma unroll
        for (int m = 0; m < 2; ++m) {
          accr[m] = zero4; accz[m] = zero4; acca[m] = zero4; accb[m] = zero4;
        }

        #pragma unroll
        for (int ks = 0; ks < 2; ++ks) {
          const unsigned char* base = wlds + boff[n] + ks * 4096;
          bf16x8 b0 = *(const bf16x8*)(base + 0 * 8192);
          bf16x8 b1 = *(const bf16x8*)(base + 1 * 8192);
          bf16x8 b2 = *(const bf16x8*)(base + 2 * 8192);
          bf16x8 b3 = *(const bf16x8*)(base + 3 * 8192);
          bf16x8 b4 = *(const bf16x8*)(base + 4 * 8192);
          bf16x8 b5 = *(const bf16x8*)(base + 5 * 8192);
          #pragma unroll
          for (int m = 0; m < 2; ++m) {
            accr[m] = __builtin_amdgcn_mfma_f32_16x16x32_bf16(ax[m][ks], b0, accr[m], 0, 0, 0);
            accr[m] = __builtin_amdgcn_mfma_f32_16x16x32_bf16(ah[m][ks], b1, accr[m], 0, 0, 0);
            accz[m] = __builtin_amdgcn_mfma_f32_16x16x32_bf16(ax[m][ks], b2, accz[m], 0, 0, 0);
            accz[m] = __builtin_amdgcn_mfma_f32_16x16x32_bf16(ah[m][ks], b3, accz[m], 0, 0, 0);
            acca[m] = __builtin_amdgcn_mfma_f32_16x16x32_bf16(ax[m][ks], b4, acca[m], 0, 0, 0);
            accb[m] = __builtin_amdgcn_mfma_f32_16x16x32_bf16(ah[m][ks], b5, accb[m], 0, 0, 0);
          }
        }

        // ---- epilogue for this n: gates + blend, direct store ----
        // D layout (HW-verified m89): col = lane&15, row = (lane>>4)*4 + j
        const int o = wn * 32 + n * 16 + lr;
        #pragma unroll
        for (int m = 0; m < 2; ++m) {
          #pragma unroll
          for (int j = 0; j < 4; ++j) {
            const int row = brow0 + m * 16 + lg * 4 + j;
            const size_t idx = ((size_t)row * UNITS + u) * HID + o;
            const float rv = fast_sigmoid(accr[m][j] + brs[n]);
            const float zv = fast_sigmoid(accz[m][j] + bzs[n]);
            const float nv = fast_tanh(acca[m][j] + bins[n] +
                                       rv * (accb[m][j] + bhns[n]));
            const float hv = h[idx];
            out[idx] = (1.0f - zv) * nv + zv * hv;
          }
        }
      }
    }
}

extern "C" void kernel_launch(void* const* d_in, const int* in_sizes, int n_in,
                              void* d_out, int out_size, void* d_ws, size_t ws_size,
                              hipStream_t stream) {
    const float* x    = (const float*)d_in[0];
    const float* h    = (const float*)d_in[1];
    const float* W_ir = (const float*)d_in[2];
    const float* b_ir = (const float*)d_in[3];
    const float* W_hr = (const float*)d_in[4];
    const float* b_hr = (const float*)d_in[5];
    const float* W_iz = (const float*)d_in[6];
    const float* b_iz = (const float*)d_in[7];
    const float* W_hz = (const float*)d_in[8];
    const float* b_hz = (const float*)d_in[9];
    const float* W_in = (const float*)d_in[10];
    const float* b_in = (const float*)d_in[11];
    const float* W_hn = (const float*)d_in[12];
    const float* b_hn = (const float*)d_in[13];
    float* out = (float*)d_out;

    gru_kernel<<<dim3(UNITS), dim3(512), 0, stream>>>(
        x, h, W_ir, b_ir, W_hr, b_hr, W_iz, b_iz, W_hz, b_hz,
        W_in, b_in, W_hn, b_hn, out);
}

// Round 6
// 60.822 us; speedup vs baseline: 2.7696x; 1.2053x over previous
//
#include <hip/hip_runtime.h>
#include <cstddef>

#define BATCH 512
#define UNITS 512
#define HID   64
#define CHUNKS 2                  // grid = 1024 blocks -> up to 3-4 blocks/CU
#define ROWS_PER_CHUNK (BATCH / CHUNKS)

typedef __bf16 bf16x8 __attribute__((ext_vector_type(8)));
typedef float  f32x4  __attribute__((ext_vector_type(4)));

__device__ __forceinline__ float fast_sigmoid(float v) {
    return 1.0f / (1.0f + __expf(-v));
}
__device__ __forceinline__ float fast_tanh(float v) {
    return 2.0f / (1.0f + __expf(-2.0f * v)) - 1.0f;
}

// Register-diet redesign (R6). Cross-round model: compiler splits the 512-reg
// unified file evenly arch/AGPR per launch_bounds ((512,2)->112, (256,3)->84,
// (256,4)->64); HW runs waves by ACTUAL arch+agpr total (steps at 64/128/256).
// R1/R5 sat at ~176-224 total -> 2 waves/SIMD -> 20-25% occupancy forever.
// Here: wave = 16 rows x 64 cols, n-outer over four 16-col fragments:
//   A-frags 16 + B transient 24 + acc 16 + hv 4 + misc ~20  ->  ~80-100 total
// -> 4 waves/SIMD target. Blocks: 512 thr, 8 waves, 128 rows/iter, 2 iters.
// Weights in LDS 48KB fragment-order + 1KB bias table; grid 1024 (CHUNKS=2).
__global__ __launch_bounds__(512, 3)
void gru_kernel(const float* __restrict__ x,    const float* __restrict__ h,
                const float* __restrict__ W_ir, const float* __restrict__ b_ir,
                const float* __restrict__ W_hr, const float* __restrict__ b_hr,
                const float* __restrict__ W_iz, const float* __restrict__ b_iz,
                const float* __restrict__ W_hz, const float* __restrict__ b_hz,
                const float* __restrict__ W_in, const float* __restrict__ b_in,
                const float* __restrict__ W_hn, const float* __restrict__ b_hn,
                float* __restrict__ out)
{
    __shared__ __align__(16) unsigned char wlds[6 * 2 * 64 * 4 * 16]; // 48 KB
    __shared__ float blds[4][64];                                     // 1 KB

    const int u     = blockIdx.x >> 1;   // unit
    const int chunk = blockIdx.x & 1;    // batch chunk (256 rows)
    const int tid  = threadIdx.x;
    const int lane = tid & 63;
    const int w    = tid >> 6;   // 0..7 : 16-row group within 128-row tile
    const int lr   = lane & 15;  // row (A) / col (B,D) within fragment
    const int lg   = lane >> 4;  // k-group 0..3

    const float* Wg[6] = {
        W_ir + (size_t)u * 64 * 64, W_hr + (size_t)u * 64 * 64,
        W_iz + (size_t)u * 64 * 64, W_hz + (size_t)u * 64 * 64,
        W_in + (size_t)u * 64 * 64, W_hn + (size_t)u * 64 * 64 };

    // ---- stage weights into LDS fragment layout (verified R5) ----
    // thread t: o_s = t&63, ig = t>>6 covers i rows ig*8..ig*8+7 (one pass/matrix)
    {
      const int o_s  = tid & 63;
      const int ig   = tid >> 6;
      const int ks_s = ig >> 2;
      const int lg_s = ig & 3;
      const int rot  = (lg_s + (o_s >> 2)) & 3;
      #pragma unroll
      for (int g = 0; g < 6; ++g) {
        const float* q = Wg[g] + (size_t)(ig * 8) * 64 + o_s;
        bf16x8 f;
        #pragma unroll
        for (int e = 0; e < 8; ++e) f[e] = (__bf16)q[(size_t)e * 64];
        const int slot = (g * 2 + ks_s) * 256 + o_s * 4 + rot;
        *(bf16x8*)(wlds + (size_t)slot * 16) = f;
      }
    }

    // ---- stage bias sums into LDS (1KB) ----
    if (tid < 64) {
      const int o = tid;
      blds[0][o] = b_ir[u * 64 + o] + b_hr[u * 64 + o];
      blds[1][o] = b_iz[u * 64 + o] + b_hz[u * 64 + o];
      blds[2][o] = b_in[u * 64 + o];
      blds[3][o] = b_hn[u * 64 + o];
    }

    __syncthreads();

    const f32x4 zero4 = { 0.0f, 0.0f, 0.0f, 0.0f };

    #pragma unroll 1
    for (int it = 0; it < ROWS_PER_CHUNK / 128; ++it) {
      const int brow0 = chunk * ROWS_PER_CHUNK + it * 128 + w * 16;

      // ---- A fragments: this wave's 16 rows of x,h (8 contiguous k/lane) ----
      bf16x8 ax[2], ah[2];
      {
        const int row = brow0 + lr;
        const float* px = x + ((size_t)row * UNITS + u) * HID;
        const float* ph = h + ((size_t)row * UNITS + u) * HID;
        #pragma unroll
        for (int ks = 0; ks < 2; ++ks) {
          const int i0 = ks * 32 + lg * 8;
          f32x4 xv0 = *(const f32x4*)(px + i0);
          f32x4 xv1 = *(const f32x4*)(px + i0 + 4);
          f32x4 hv0 = *(const f32x4*)(ph + i0);
          f32x4 hv1 = *(const f32x4*)(ph + i0 + 4);
          bf16x8 fx, fh;
          #pragma unroll
          for (int e = 0; e < 4; ++e) {
            fx[e]     = (__bf16)xv0[e];
            fx[4 + e] = (__bf16)xv1[e];
            fh[e]     = (__bf16)hv0[e];
            fh[4 + e] = (__bf16)hv1[e];
          }
          ax[ks] = fx;
          ah[ks] = fh;
        }
      }

      // ---- n-outer: one 16-col fragment at a time, 16 acc regs live ----
      #pragma unroll 1
      for (int n = 0; n < 4; ++n) {
        const int o = n * 16 + lr;

        // issue epilogue h reloads early: latency hides under the 12 MFMAs
        float hv[4];
        #pragma unroll
        for (int j = 0; j < 4; ++j) {
          const int row = brow0 + lg * 4 + j;
          hv[j] = h[((size_t)row * UNITS + u) * HID + o];
        }
        const float br = blds[0][o];
        const float bz = blds[1][o];
        const float bi = blds[2][o];
        const float bh = blds[3][o];

        const int boff = (o * 4 + ((lg + (o >> 2)) & 3)) * 16;

        f32x4 accr = zero4, accz = zero4, acca = zero4, accb = zero4;
        #pragma unroll
        for (int ks = 0; ks < 2; ++ks) {
          const unsigned char* base = wlds + boff + ks * 4096;
          bf16x8 b0 = *(const bf16x8*)(base + 0 * 8192);
          bf16x8 b1 = *(const bf16x8*)(base + 1 * 8192);
          bf16x8 b2 = *(const bf16x8*)(base + 2 * 8192);
          bf16x8 b3 = *(const bf16x8*)(base + 3 * 8192);
          bf16x8 b4 = *(const bf16x8*)(base + 4 * 8192);
          bf16x8 b5 = *(const bf16x8*)(base + 5 * 8192);
          accr = __builtin_amdgcn_mfma_f32_16x16x32_bf16(ax[ks], b0, accr, 0, 0, 0);
          accr = __builtin_amdgcn_mfma_f32_16x16x32_bf16(ah[ks], b1, accr, 0, 0, 0);
          accz = __builtin_amdgcn_mfma_f32_16x16x32_bf16(ax[ks], b2, accz, 0, 0, 0);
          accz = __builtin_amdgcn_mfma_f32_16x16x32_bf16(ah[ks], b3, accz, 0, 0, 0);
          acca = __builtin_amdgcn_mfma_f32_16x16x32_bf16(ax[ks], b4, acca, 0, 0, 0);
          accb = __builtin_amdgcn_mfma_f32_16x16x32_bf16(ah[ks], b5, accb, 0, 0, 0);
        }

        // ---- epilogue for this n ----
        // D layout (HW-verified m89): col = lane&15, row = (lane>>4)*4 + j
        #pragma unroll
        for (int j = 0; j < 4; ++j) {
          const int row = brow0 + lg * 4 + j;
          const size_t idx = ((size_t)row * UNITS + u) * HID + o;
          const float rv = fast_sigmoid(accr[j] + br);
          const float zv = fast_sigmoid(accz[j] + bz);
          const float nv = fast_tanh(acca[j] + bi + rv * (accb[j] + bh));
          out[idx] = (1.0f - zv) * nv + zv * hv[j];
        }
      }
    }
}

extern "C" void kernel_launch(void* const* d_in, const int* in_sizes, int n_in,
                              void* d_out, int out_size, void* d_ws, size_t ws_size,
                              hipStream_t stream) {
    const float* x    = (const float*)d_in[0];
    const float* h    = (const float*)d_in[1];
    const float* W_ir = (const float*)d_in[2];
    const float* b_ir = (const float*)d_in[3];
    const float* W_hr = (const float*)d_in[4];
    const float* b_hr = (const float*)d_in[5];
    const float* W_iz = (const float*)d_in[6];
    const float* b_iz = (const float*)d_in[7];
    const float* W_hz = (const float*)d_in[8];
    const float* b_hz = (const float*)d_in[9];
    const float* W_in = (const float*)d_in[10];
    const float* b_in = (const float*)d_in[11];
    const float* W_hn = (const float*)d_in[12];
    const float* b_hn = (const float*)d_in[13];
    float* out = (float*)d_out;

    gru_kernel<<<dim3(UNITS * CHUNKS), dim3(512), 0, stream>>>(
        x, h, W_ir, b_ir, W_hr, b_hr, W_iz, b_iz, W_hz, b_hz,
        W_in, b_in, W_hn, b_hn, out);
}